// Round 8
// baseline (163.690 us; speedup 1.0000x reference)
//
#include <hip/hip_runtime.h>

#define NN 256
#define NF 16

typedef _Float16 half4 __attribute__((ext_vector_type(4)));
typedef float f32x4 __attribute__((ext_vector_type(4)));

// ws layout (floats): ping-pong x/h/su/sv
#define XA_OFF 0
#define XB_OFF 32768
#define HA_OFF 65536
#define HB_OFF 196608
#define SUA_OFF 327680
#define SVA_OFF 458752
#define SUB_OFF 589824
#define SVB_OFF 720896

// R21: MEASUREMENT ROUND. R16 pipeline verbatim (proven 131.8us), but
// layer_kernel takes a `reps` count and L1 runs reps=3: the whole body is
// idempotent (reads h_in/x_in/su_in/sv_in, writes separate out buffers;
// every rep recomputes identical values), so L1's dispatch lasts ~49us,
// exceeding the ~40us harness poison-fills and entering rocprof's top-5 —
// giving us the layer kernel's MEASURED VALUBusy / MfmaUtil / Occupancy /
// VGPR_Count for the first time. Evidence so far is contradictory:
// kernels are 16.4us each (R17 probe), but LDS staging (R14), and 2x
// occupancy (R20) are both null — need real counters to pick the attack.
__global__ __launch_bounds__(256)
void layer0_kernel(const float* __restrict__ xs, const float* __restrict__ vs,
                   const float* __restrict__ charges,
                   const float* __restrict__ W_in, const float* __restrict__ b_in,
                   const float* __restrict__ W_v, const float* __restrict__ We1_l,
                   const float* __restrict__ be1_l, const float* __restrict__ We2_l,
                   const float* __restrict__ be2_l, const float* __restrict__ Wx_l,
                   const float* __restrict__ Wh1_l, const float* __restrict__ bh1_l,
                   const float* __restrict__ We1_n, const float* __restrict__ be1_n,
                   float* __restrict__ x_out, float* __restrict__ h_out,
                   float* __restrict__ su_out, float* __restrict__ sv_out) {
    __shared__ __align__(16) float sSU[NN * NF];   // 16 KB: su0 (this batch)
    __shared__ __align__(16) float sX[NN * 4];     // 4 KB: x0 padded
    __shared__ __align__(16) float sHg[64 * NF];   // 4 KB: init scratch
    __shared__ float sWs[256], sWd[256];           // L0 We1 src/dst
    __shared__ __align__(16) float sSV8[8][NF];    // own-octet sv0
    __shared__ __align__(16) float sH8[8][NF + 1]; // own-octet h0
    __shared__ float sWh1s[512];
    __shared__ float sWa[256], sWb[256];           // next-layer We1^T
    __shared__ float sbe1n[NF];
    __shared__ float sh_new[8][NF + 1];
    __shared__ float sg[8][NF];

    const int tid  = threadIdx.x;
    const int b    = blockIdx.x >> 5;
    const int oct  = blockIdx.x & 31;
    const int n0l  = 8 * oct;
    const size_t n0 = (size_t)b * NN + n0l;
    const int w    = tid >> 6;
    const int lane = tid & 63;
    const int c    = lane & 15;
    const int g    = lane >> 4;

    // ---- stage all weights + x (no cross-block data anywhere) ----
    sWs[tid] = We1_l[tid];          // L0 src rows [f][k]
    sWd[tid] = We1_l[256 + tid];    // L0 dst rows [f][k]
    sWh1s[tid]       = Wh1_l[tid];
    sWh1s[256 + tid] = Wh1_l[256 + tid];
    {
        const int f = tid >> 4, kk = tid & 15;
        sWa[kk * NF + f] = We1_n[tid];           // next-layer WsrcT
        sWb[kk * NF + f] = We1_n[256 + tid];     // next-layer WdstT
        if (tid < NF) sbe1n[tid] = be1_n[tid];
    }
    {   // x0 padded stride-4 from xs stride-3
        const size_t base = ((size_t)b * NN + tid) * 3;
        sX[tid * 4 + 0] = xs[base + 0];
        sX[tid * 4 + 1] = xs[base + 1];
        sX[tid * 4 + 2] = xs[base + 2];
        sX[tid * 4 + 3] = 0.f;
    }

    // ---- init: h0 (own octet), su0 (all 256 nodes), sv0 (own octet) ----
    const int nl = tid >> 4, k = tid & 15;
    const float win  = W_in[k];
    const float bin  = b_in[k];
    const float be1k = be1_l[k];
    const int i0 = n0l >> 6;              // 64-node group holding our octet
    const int r0 = (n0l & 63) >> 4;       // 16-row within group
    const int halfsel = (n0l >> 3) & 1;   // 8-half within the 16-row
    const int own = ((nl >> 3) == halfsel);
#pragma unroll
    for (int i = 0; i < 4; ++i) {
#pragma unroll
        for (int r = 0; r < 4; ++r) {
            const float cq = charges[(size_t)b * NN + 64 * i + 16 * r + nl];
            const float hf = fmaxf(fmaf(cq, win, bin), 0.f);
            sHg[(16 * r + nl) * NF + k] = hf;
            if (i == i0 && r == r0 && own) sH8[nl & 7][k] = hf;
        }
        __syncthreads();
#pragma unroll
        for (int r = 0; r < 4; ++r) {
            const float4* hn = (const float4*)&sHg[(16 * r + nl) * NF];
            const float4 h0q = hn[0], h1q = hn[1], h2q = hn[2], h3q = hn[3];
            float u = 0.f;
#pragma unroll
            for (int q = 0; q < 4; ++q) {
                const float4 hq = (q == 0) ? h0q : (q == 1) ? h1q : (q == 2) ? h2q : h3q;
                u = fmaf(hq.x, sWs[(4 * q + 0) * NF + k], u);
                u = fmaf(hq.y, sWs[(4 * q + 1) * NF + k], u);
                u = fmaf(hq.z, sWs[(4 * q + 2) * NF + k], u);
                u = fmaf(hq.w, sWs[(4 * q + 3) * NF + k], u);
            }
            sSU[(64 * i + 16 * r + nl) * NF + k] = u;
            if (i == i0 && r == r0 && own) {
                float v = be1k;
#pragma unroll
                for (int q = 0; q < 4; ++q) {
                    const float4 hq = (q == 0) ? h0q : (q == 1) ? h1q : (q == 2) ? h2q : h3q;
                    v = fmaf(hq.x, sWd[(4 * q + 0) * NF + k], v);
                    v = fmaf(hq.y, sWd[(4 * q + 1) * NF + k], v);
                    v = fmaf(hq.z, sWd[(4 * q + 2) * NF + k], v);
                    v = fmaf(hq.w, sWd[(4 * q + 3) * NF + k], v);
                }
                sSV8[nl & 7][k] = v;
            }
        }
        __syncthreads();
    }

    // ---- layer-0 body (inputs all LDS-local) ----
    const int j0 = n0l + w, j1 = n0l + 4 + w;
    const float4 xj0 = *(const float4*)&sX[4 * j0];
    const float4 xj1 = *(const float4*)&sX[4 * j1];
    half4 afrag;
    afrag.x = (_Float16)We2_l[(4 * g + 0) * NF + c];
    afrag.y = (_Float16)We2_l[(4 * g + 1) * NF + c];
    afrag.z = (_Float16)We2_l[(4 * g + 2) * NF + c];
    afrag.w = (_Float16)We2_l[(4 * g + 3) * NF + c];
    const float4 v40 = *(const float4*)&sSV8[w][4 * g];
    const float4 v41 = *(const float4*)&sSV8[4 + w][4 * g];
    const float4 wr4  = *(const float4*)(We1_l + 512 + 4 * g);
    const float4 be2f = *(const float4*)(be2_l + 4 * g);
    const float4 wxf  = *(const float4*)(Wx_l + 4 * g);
    f32x4 cb;
    cb.x = be2f.x; cb.y = be2f.y; cb.z = be2f.z; cb.w = be2f.w;

    float Sw0 = 0.f, Swx0 = 0.f, Swy0 = 0.f, Swz0 = 0.f;
    float Sw1 = 0.f, Swx1 = 0.f, Swy1 = 0.f, Swz1 = 0.f;
    float g00 = 0.f, g01 = 0.f, g02 = 0.f, g03 = 0.f;
    float g10 = 0.f, g11 = 0.f, g12 = 0.f, g13 = 0.f;

    const float* su_l = &sSU[c * NF + 4 * g];
    const float* x_l  = &sX[4 * c];

#pragma unroll 2
    for (int t = 0; t < 16; ++t) {
        const float4 u4  = *(const float4*)(su_l + 256 * t);
        const float4 xs4 = *(const float4*)(x_l + 64 * t);
        const int s = 16 * t + c;
        {
            const float dx = xj0.x - xs4.x, dy = xj0.y - xs4.y, dz = xj0.z - xs4.z;
            const float r2 = fmaf(dx, dx, fmaf(dy, dy, dz * dz));
            const float m0 = fmaxf(fmaf(r2, wr4.x, u4.x + v40.x), 0.f);
            const float m1 = fmaxf(fmaf(r2, wr4.y, u4.y + v40.y), 0.f);
            const float m2 = fmaxf(fmaf(r2, wr4.z, u4.z + v40.z), 0.f);
            const float m3 = fmaxf(fmaf(r2, wr4.w, u4.w + v40.w), 0.f);
            half4 bfrag;
            bfrag.x = (_Float16)m0; bfrag.y = (_Float16)m1;
            bfrag.z = (_Float16)m2; bfrag.w = (_Float16)m3;
            const f32x4 acc = __builtin_amdgcn_mfma_f32_16x16x16f16(afrag, bfrag, cb, 0, 0, 0);
            const float e0 = fmaxf(acc.x, 0.f);
            const float e1 = fmaxf(acc.y, 0.f);
            const float e2 = fmaxf(acc.z, 0.f);
            const float e3 = fmaxf(acc.w, 0.f);
            float wp = e0 * wxf.x;
            wp = fmaf(e1, wxf.y, wp);
            wp = fmaf(e2, wxf.z, wp);
            wp = fmaf(e3, wxf.w, wp);
            const float gsel = (s != j0) ? 1.f : 0.f;
            g00 = fmaf(e0, gsel, g00);
            g01 = fmaf(e1, gsel, g01);
            g02 = fmaf(e2, gsel, g02);
            g03 = fmaf(e3, gsel, g03);
            Sw0 += wp;
            Swx0 = fmaf(wp, xs4.x, Swx0);
            Swy0 = fmaf(wp, xs4.y, Swy0);
            Swz0 = fmaf(wp, xs4.z, Swz0);
        }
        {
            const float dx = xj1.x - xs4.x, dy = xj1.y - xs4.y, dz = xj1.z - xs4.z;
            const float r2 = fmaf(dx, dx, fmaf(dy, dy, dz * dz));
            const float m0 = fmaxf(fmaf(r2, wr4.x, u4.x + v41.x), 0.f);
            const float m1 = fmaxf(fmaf(r2, wr4.y, u4.y + v41.y), 0.f);
            const float m2 = fmaxf(fmaf(r2, wr4.z, u4.z + v41.z), 0.f);
            const float m3 = fmaxf(fmaf(r2, wr4.w, u4.w + v41.w), 0.f);
            half4 bfrag;
            bfrag.x = (_Float16)m0; bfrag.y = (_Float16)m1;
            bfrag.z = (_Float16)m2; bfrag.w = (_Float16)m3;
            const f32x4 acc = __builtin_amdgcn_mfma_f32_16x16x16f16(afrag, bfrag, cb, 0, 0, 0);
            const float e0 = fmaxf(acc.x, 0.f);
            const float e1 = fmaxf(acc.y, 0.f);
            const float e2 = fmaxf(acc.z, 0.f);
            const float e3 = fmaxf(acc.w, 0.f);
            float wp = e0 * wxf.x;
            wp = fmaf(e1, wxf.y, wp);
            wp = fmaf(e2, wxf.z, wp);
            wp = fmaf(e3, wxf.w, wp);
            const float gsel = (s != j1) ? 1.f : 0.f;
            g10 = fmaf(e0, gsel, g10);
            g11 = fmaf(e1, gsel, g11);
            g12 = fmaf(e2, gsel, g12);
            g13 = fmaf(e3, gsel, g13);
            Sw1 += wp;
            Swx1 = fmaf(wp, xs4.x, Swx1);
            Swy1 = fmaf(wp, xs4.y, Swy1);
            Swz1 = fmaf(wp, xs4.z, Swz1);
        }
    }

#pragma unroll
    for (int off = 1; off < 64; off <<= 1) {
        Sw0  += __shfl_xor(Sw0,  off, 64);  Sw1  += __shfl_xor(Sw1,  off, 64);
        Swx0 += __shfl_xor(Swx0, off, 64);  Swx1 += __shfl_xor(Swx1, off, 64);
        Swy0 += __shfl_xor(Swy0, off, 64);  Swy1 += __shfl_xor(Swy1, off, 64);
        Swz0 += __shfl_xor(Swz0, off, 64);  Swz1 += __shfl_xor(Swz1, off, 64);
    }
#pragma unroll
    for (int off = 1; off < 16; off <<= 1) {
        g00 += __shfl_xor(g00, off, 64);  g10 += __shfl_xor(g10, off, 64);
        g01 += __shfl_xor(g01, off, 64);  g11 += __shfl_xor(g11, off, 64);
        g02 += __shfl_xor(g02, off, 64);  g12 += __shfl_xor(g12, off, 64);
        g03 += __shfl_xor(g03, off, 64);  g13 += __shfl_xor(g13, off, 64);
    }
    if ((lane & 15) == 0) {
        *(float4*)&sg[w][4 * g]     = make_float4(g00, g01, g02, g03);
        *(float4*)&sg[w + 4][4 * g] = make_float4(g10, g11, g12, g13);
    }
    __syncthreads();

    const int is0 = (lane < 16);
    const int is1 = (lane >= 32 && lane < 48);
    if (is0 || is1) {
        const int f = lane & 15;
        const int slot = is0 ? w : (w + 4);
        const int jm   = is0 ? j0 : j1;
        const float SwS = is0 ? Sw0  : Sw1;
        const float SxS = is0 ? Swx0 : Swx1;
        const float SyS = is0 ? Swy0 : Swy1;
        const float SzS = is0 ? Swz0 : Swz1;
        const float4 xjm = is0 ? xj0 : xj1;
        const size_t nj = (size_t)b * NN + jm;
        float hd = bh1_l[f];
        float hv = 0.f;
#pragma unroll
        for (int kk = 0; kk < NF; ++kk) {
            const float hjk = sH8[slot][kk];
            hd = fmaf(hjk, sWh1s[kk * NF + f], hd);
            hv = fmaf(hjk, W_v[kk], hv);
        }
#pragma unroll
        for (int kk = 0; kk < NF; ++kk) {
            hd = fmaf(sg[slot][kk], sWh1s[(NF + kk) * NF + f], hd);
        }
        const float hnew = sH8[slot][f] + fmaxf(hd, 0.f);
        sh_new[slot][f] = hnew;
        h_out[nj * NF + f] = hnew;
        if (f < 3) {
            const float xc = (f == 0) ? xjm.x : ((f == 1) ? xjm.y : xjm.z);
            const float Sc = (f == 0) ? SxS  : ((f == 1) ? SyS  : SzS);
            const float agg = (SwS * xc - Sc) * (1.f / 255.f);
            const float xnew = xc + agg + vs[nj * 3 + f] * hv;
            x_out[nj * 4 + f] = xnew;
        }
        if (f == 3) x_out[nj * 4 + 3] = 0.f;
    }

    __syncthreads();
    if (tid < 128) {
        const int jd = tid >> 4, kk = tid & 15;
        float u = 0.f, v = sbe1n[kk];
#pragma unroll
        for (int f = 0; f < NF; ++f) {
            const float hf = sh_new[jd][f];
            u = fmaf(hf, sWa[kk * NF + f], u);
            v = fmaf(hf, sWb[kk * NF + f], v);
        }
        su_out[(n0 + jd) * NF + kk] = u;
        sv_out[(n0 + jd) * NF + kk] = v;
    }
}

// R14/R16 layer kernel + idempotent `reps` loop (identical values rewritten
// each rep; races between rep r's reads and rep r+1's identical-value
// staging writes are benign, and a syncthreads heads each rep anyway).
__global__ __launch_bounds__(256)
void layer_kernel(const float* __restrict__ x_in, const float* __restrict__ h_in,
                  const float* __restrict__ su_in, const float* __restrict__ sv_in,
                  float* __restrict__ x_out, float* __restrict__ h_out,
                  float* __restrict__ su_out, float* __restrict__ sv_out,
                  const float* __restrict__ vs, const float* __restrict__ Wv_l,
                  const float* __restrict__ We1_l, const float* __restrict__ We2_l,
                  const float* __restrict__ be2_l, const float* __restrict__ Wx_l,
                  const float* __restrict__ Wh1_l, const float* __restrict__ bh1_l,
                  const float* __restrict__ We1_n, const float* __restrict__ be1_n,
                  int final_layer, int reps) {
    __shared__ __align__(16) float sSU[NN * NF];
    __shared__ __align__(16) float sX[NN * 4];
    __shared__ float sWh1s[512];
    __shared__ float sWa[256];
    __shared__ float sWb[256];
    __shared__ float sbe1n[NF];
    __shared__ float sh_new[8][NF + 1];
    __shared__ float sg[8][NF];

    const int tid  = threadIdx.x;
    const int b    = blockIdx.x >> 5;
    const int oct  = blockIdx.x & 31;
    const int n0l  = 8 * oct;
    const size_t n0 = (size_t)b * NN + n0l;
    const int w    = tid >> 6;
    const int lane = tid & 63;
    const int c    = lane & 15;
    const int g    = lane >> 4;

    for (int rep = 0; rep < reps; ++rep) {
        __syncthreads();
        sWh1s[tid]       = Wh1_l[tid];
        sWh1s[256 + tid] = Wh1_l[256 + tid];
        if (!final_layer) {
            const int f = tid >> 4, k = tid & 15;
            sWa[k * NF + f] = We1_n[tid];
            sWb[k * NF + f] = We1_n[256 + tid];
            if (tid < NF) sbe1n[tid] = be1_n[tid];
        }
        {
            const float4* gsu = (const float4*)(su_in + (size_t)b * NN * NF);
            float4* lsu = (float4*)sSU;
            lsu[tid]        = gsu[tid];
            lsu[256 + tid]  = gsu[256 + tid];
            lsu[512 + tid]  = gsu[512 + tid];
            lsu[768 + tid]  = gsu[768 + tid];
            const float4* gx = (const float4*)(x_in + (size_t)b * NN * 4);
            ((float4*)sX)[tid] = gx[tid];
        }
        __syncthreads();

        const int j0 = n0l + w, j1 = n0l + 4 + w;
        const float4 xj0 = *(const float4*)&sX[4 * j0];
        const float4 xj1 = *(const float4*)&sX[4 * j1];
        half4 afrag;
        afrag.x = (_Float16)We2_l[(4 * g + 0) * NF + c];
        afrag.y = (_Float16)We2_l[(4 * g + 1) * NF + c];
        afrag.z = (_Float16)We2_l[(4 * g + 2) * NF + c];
        afrag.w = (_Float16)We2_l[(4 * g + 3) * NF + c];
        const float4 v40  = *(const float4*)(sv_in + ((size_t)b * NN + j0) * NF + 4 * g);
        const float4 v41  = *(const float4*)(sv_in + ((size_t)b * NN + j1) * NF + 4 * g);
        const float4 wr4  = *(const float4*)(We1_l + 512 + 4 * g);
        const float4 be2f = *(const float4*)(be2_l + 4 * g);
        const float4 wxf  = *(const float4*)(Wx_l + 4 * g);
        f32x4 cb;
        cb.x = be2f.x; cb.y = be2f.y; cb.z = be2f.z; cb.w = be2f.w;

        float Sw0 = 0.f, Swx0 = 0.f, Swy0 = 0.f, Swz0 = 0.f;
        float Sw1 = 0.f, Swx1 = 0.f, Swy1 = 0.f, Swz1 = 0.f;
        float g00 = 0.f, g01 = 0.f, g02 = 0.f, g03 = 0.f;
        float g10 = 0.f, g11 = 0.f, g12 = 0.f, g13 = 0.f;

        const float* su_l = &sSU[c * NF + 4 * g];
        const float* x_l  = &sX[4 * c];

#pragma unroll 2
        for (int t = 0; t < 16; ++t) {
            const float4 u4  = *(const float4*)(su_l + 256 * t);
            const float4 xs4 = *(const float4*)(x_l + 64 * t);
            const int s = 16 * t + c;
            {
                const float dx = xj0.x - xs4.x, dy = xj0.y - xs4.y, dz = xj0.z - xs4.z;
                const float r2 = fmaf(dx, dx, fmaf(dy, dy, dz * dz));
                const float m0 = fmaxf(fmaf(r2, wr4.x, u4.x + v40.x), 0.f);
                const float m1 = fmaxf(fmaf(r2, wr4.y, u4.y + v40.y), 0.f);
                const float m2 = fmaxf(fmaf(r2, wr4.z, u4.z + v40.z), 0.f);
                const float m3 = fmaxf(fmaf(r2, wr4.w, u4.w + v40.w), 0.f);
                half4 bfrag;
                bfrag.x = (_Float16)m0; bfrag.y = (_Float16)m1;
                bfrag.z = (_Float16)m2; bfrag.w = (_Float16)m3;
                const f32x4 acc = __builtin_amdgcn_mfma_f32_16x16x16f16(afrag, bfrag, cb, 0, 0, 0);
                const float e0 = fmaxf(acc.x, 0.f);
                const float e1 = fmaxf(acc.y, 0.f);
                const float e2 = fmaxf(acc.z, 0.f);
                const float e3 = fmaxf(acc.w, 0.f);
                float wp = e0 * wxf.x;
                wp = fmaf(e1, wxf.y, wp);
                wp = fmaf(e2, wxf.z, wp);
                wp = fmaf(e3, wxf.w, wp);
                const float gsel = (s != j0) ? 1.f : 0.f;
                g00 = fmaf(e0, gsel, g00);
                g01 = fmaf(e1, gsel, g01);
                g02 = fmaf(e2, gsel, g02);
                g03 = fmaf(e3, gsel, g03);
                Sw0 += wp;
                Swx0 = fmaf(wp, xs4.x, Swx0);
                Swy0 = fmaf(wp, xs4.y, Swy0);
                Swz0 = fmaf(wp, xs4.z, Swz0);
            }
            {
                const float dx = xj1.x - xs4.x, dy = xj1.y - xs4.y, dz = xj1.z - xs4.z;
                const float r2 = fmaf(dx, dx, fmaf(dy, dy, dz * dz));
                const float m0 = fmaxf(fmaf(r2, wr4.x, u4.x + v41.x), 0.f);
                const float m1 = fmaxf(fmaf(r2, wr4.y, u4.y + v41.y), 0.f);
                const float m2 = fmaxf(fmaf(r2, wr4.z, u4.z + v41.z), 0.f);
                const float m3 = fmaxf(fmaf(r2, wr4.w, u4.w + v41.w), 0.f);
                half4 bfrag;
                bfrag.x = (_Float16)m0; bfrag.y = (_Float16)m1;
                bfrag.z = (_Float16)m2; bfrag.w = (_Float16)m3;
                const f32x4 acc = __builtin_amdgcn_mfma_f32_16x16x16f16(afrag, bfrag, cb, 0, 0, 0);
                const float e0 = fmaxf(acc.x, 0.f);
                const float e1 = fmaxf(acc.y, 0.f);
                const float e2 = fmaxf(acc.z, 0.f);
                const float e3 = fmaxf(acc.w, 0.f);
                float wp = e0 * wxf.x;
                wp = fmaf(e1, wxf.y, wp);
                wp = fmaf(e2, wxf.z, wp);
                wp = fmaf(e3, wxf.w, wp);
                const float gsel = (s != j1) ? 1.f : 0.f;
                g10 = fmaf(e0, gsel, g10);
                g11 = fmaf(e1, gsel, g11);
                g12 = fmaf(e2, gsel, g12);
                g13 = fmaf(e3, gsel, g13);
                Sw1 += wp;
                Swx1 = fmaf(wp, xs4.x, Swx1);
                Swy1 = fmaf(wp, xs4.y, Swy1);
                Swz1 = fmaf(wp, xs4.z, Swz1);
            }
        }

#pragma unroll
        for (int off = 1; off < 64; off <<= 1) {
            Sw0  += __shfl_xor(Sw0,  off, 64);  Sw1  += __shfl_xor(Sw1,  off, 64);
            Swx0 += __shfl_xor(Swx0, off, 64);  Swx1 += __shfl_xor(Swx1, off, 64);
            Swy0 += __shfl_xor(Swy0, off, 64);  Swy1 += __shfl_xor(Swy1, off, 64);
            Swz0 += __shfl_xor(Swz0, off, 64);  Swz1 += __shfl_xor(Swz1, off, 64);
        }
#pragma unroll
        for (int off = 1; off < 16; off <<= 1) {
            g00 += __shfl_xor(g00, off, 64);  g10 += __shfl_xor(g10, off, 64);
            g01 += __shfl_xor(g01, off, 64);  g11 += __shfl_xor(g11, off, 64);
            g02 += __shfl_xor(g02, off, 64);  g12 += __shfl_xor(g12, off, 64);
            g03 += __shfl_xor(g03, off, 64);  g13 += __shfl_xor(g13, off, 64);
        }
        if ((lane & 15) == 0) {
            *(float4*)&sg[w][4 * g]     = make_float4(g00, g01, g02, g03);
            *(float4*)&sg[w + 4][4 * g] = make_float4(g10, g11, g12, g13);
        }
        __syncthreads();

        const int is0 = (lane < 16);
        const int is1 = (lane >= 32 && lane < 48);
        if (is0 || is1) {
            const int f = lane & 15;
            const int slot = is0 ? w : (w + 4);
            const int jm   = is0 ? j0 : j1;
            const float SwS = is0 ? Sw0  : Sw1;
            const float SxS = is0 ? Swx0 : Swx1;
            const float SyS = is0 ? Swy0 : Swy1;
            const float SzS = is0 ? Swz0 : Swz1;
            const float4 xjm = is0 ? xj0 : xj1;
            const size_t nj = (size_t)b * NN + jm;
            float hd = bh1_l[f];
            float hv = 0.f;
#pragma unroll
            for (int k = 0; k < NF; ++k) {
                const float hjk = h_in[nj * NF + k];
                hd = fmaf(hjk, sWh1s[k * NF + f], hd);
                hv = fmaf(hjk, Wv_l[k], hv);
            }
#pragma unroll
            for (int k = 0; k < NF; ++k) {
                hd = fmaf(sg[slot][k], sWh1s[(NF + k) * NF + f], hd);
            }
            const float hnew = h_in[nj * NF + f] + fmaxf(hd, 0.f);
            sh_new[slot][f] = hnew;
            if (!final_layer) h_out[nj * NF + f] = hnew;
            if (f < 3) {
                const float xc = (f == 0) ? xjm.x : ((f == 1) ? xjm.y : xjm.z);
                const float Sc = (f == 0) ? SxS  : ((f == 1) ? SyS  : SzS);
                const float agg = (SwS * xc - Sc) * (1.f / 255.f);
                const float xnew = xc + agg + vs[nj * 3 + f] * hv;
                if (final_layer) x_out[nj * 3 + f] = xnew;
                else             x_out[nj * 4 + f] = xnew;
            }
            if (!final_layer && f == 3) x_out[nj * 4 + 3] = 0.f;
        }

        if (!final_layer) {
            __syncthreads();
            if (tid < 128) {
                const int jd = tid >> 4, k = tid & 15;
                float u = 0.f, v = sbe1n[k];
#pragma unroll
                for (int f = 0; f < NF; ++f) {
                    const float hf = sh_new[jd][f];
                    u = fmaf(hf, sWa[k * NF + f], u);
                    v = fmaf(hf, sWb[k * NF + f], v);
                }
                su_out[(n0 + jd) * NF + k] = u;
                sv_out[(n0 + jd) * NF + k] = v;
            }
        }
    }
}

extern "C" void kernel_launch(void* const* d_in, const int* in_sizes, int n_in,
                              void* d_out, int out_size, void* d_ws, size_t ws_size,
                              hipStream_t stream) {
    const float* xs      = (const float*)d_in[0];
    const float* vs      = (const float*)d_in[1];
    const float* charges = (const float*)d_in[2];
    const float* W_in    = (const float*)d_in[3];
    const float* b_in    = (const float*)d_in[4];
    const float* W_v     = (const float*)d_in[5];
    const float* We1     = (const float*)d_in[6];
    const float* be1     = (const float*)d_in[7];
    const float* We2     = (const float*)d_in[8];
    const float* be2     = (const float*)d_in[9];
    const float* Wx      = (const float*)d_in[10];
    const float* Wh1     = (const float*)d_in[11];
    const float* bh1     = (const float*)d_in[12];
    // d_in[13]=src, d_in[14]=dst: fully-connected pattern, computed analytically.

    float* ws = (float*)d_ws;
    float* xA  = ws + XA_OFF;
    float* xB  = ws + XB_OFF;
    float* hA  = ws + HA_OFF;
    float* hB  = ws + HB_OFF;
    float* suA = ws + SUA_OFF;
    float* svA = ws + SVA_OFF;
    float* suB = ws + SUB_OFF;
    float* svB = ws + SVB_OFF;
    float* out = (float*)d_out;

    // L0 (init fused, R16-verbatim): writes xA, hA, suA, svA
    hipLaunchKernelGGL(layer0_kernel, dim3(1024), dim3(256), 0, stream,
                       xs, vs, charges, W_in, b_in,
                       W_v + 0 * 16, We1 + 0 * 528, be1 + 0 * 16, We2 + 0 * 256,
                       be2 + 0 * 16, Wx + 0 * 16, Wh1 + 0 * 512, bh1 + 0 * 16,
                       We1 + 1 * 528, be1 + 1 * 16,
                       xA, hA, suA, svA);
    // L1 with reps=3 (idempotent; pushes this dispatch past the 40us fills
    // into rocprof's top-5 so we finally see its counters)
    hipLaunchKernelGGL(layer_kernel, dim3(1024), dim3(256), 0, stream,
                       xA, hA, suA, svA, xB, hB, suB, svB,
                       vs, W_v + 1 * 16, We1 + 1 * 528, We2 + 1 * 256,
                       be2 + 1 * 16, Wx + 1 * 16, Wh1 + 1 * 512, bh1 + 1 * 16,
                       We1 + 2 * 528, be1 + 2 * 16, 0, 3);
    // L2 (final, reps=1)
    hipLaunchKernelGGL(layer_kernel, dim3(1024), dim3(256), 0, stream,
                       xB, hB, suB, svB, out, hA, suA, svA,
                       vs, W_v + 2 * 16, We1 + 2 * 528, We2 + 2 * 256,
                       be2 + 2 * 16, Wx + 2 * 16, Wh1 + 2 * 512, bh1 + 2 * 16,
                       We1 + 2 * 528, be1 + 2 * 16, 1, 1);
}

// Round 9
// 130.239 us; speedup vs baseline: 1.2568x; 1.2568x over previous
//
#include <hip/hip_runtime.h>

#define NN 256
#define NF 16

typedef _Float16 half4 __attribute__((ext_vector_type(4)));
typedef _Float16 h2 __attribute__((ext_vector_type(2)));
typedef float f32x4 __attribute__((ext_vector_type(4)));

// ws layout (floats): ping-pong x/h/su/sv
#define XA_OFF 0
#define XB_OFF 32768
#define HA_OFF 65536
#define HB_OFF 196608
#define SUA_OFF 327680
#define SVA_OFF 458752
#define SUB_OFF 589824
#define SVB_OFF 720896

// R22: packed-f16 m-path. R21 counters: VALUBusy 61%, MfmaUtil 4.5%, HBM 1.2%,
// bank-conflict ~5% -> VALU-ISSUE-BOUND (explains R14/R20 nulls: staging and
// occupancy don't matter when the issue port is saturated). Fix: compute m in
// f16 with v_pk_* (absmax headroom 0.5 vs 9.6 threshold; m feeds MFMA as f16
// anyway): su staged to LDS as f16, padded [NN][20] rows (kills the 32-bank
// aliasing), v/wr pre-packed; m-path = 2 pk_add + 2 pk_fma + 2 pk_max + 1 cvt
// vs ~18 scalar ops. r2 via |xj|^2+|xs|^2-2xj.xs with |x|^2 staged in the
// padded w slot (4 ops vs 6). Same loop body in L0 and L1/L2.
__global__ __launch_bounds__(256)
void layer0_kernel(const float* __restrict__ xs, const float* __restrict__ vs,
                   const float* __restrict__ charges,
                   const float* __restrict__ W_in, const float* __restrict__ b_in,
                   const float* __restrict__ W_v, const float* __restrict__ We1_l,
                   const float* __restrict__ be1_l, const float* __restrict__ We2_l,
                   const float* __restrict__ be2_l, const float* __restrict__ Wx_l,
                   const float* __restrict__ Wh1_l, const float* __restrict__ bh1_l,
                   const float* __restrict__ We1_n, const float* __restrict__ be1_n,
                   float* __restrict__ x_out, float* __restrict__ h_out,
                   float* __restrict__ su_out, float* __restrict__ sv_out) {
    __shared__ __align__(16) _Float16 sSUh[NN][20];  // 10 KB: su0 as f16, padded
    __shared__ __align__(16) float sX[NN * 4];       // 4 KB: x0, w = |x|^2
    __shared__ __align__(16) float sHg[64 * NF];     // 4 KB: init scratch
    __shared__ float sWs[256], sWd[256];             // L0 We1 src/dst
    __shared__ __align__(16) float sSV8[8][NF];      // own-octet sv0
    __shared__ __align__(16) float sH8[8][NF + 1];   // own-octet h0
    __shared__ float sWh1s[512];
    __shared__ float sWa[256], sWb[256];             // next-layer We1^T
    __shared__ float sbe1n[NF];
    __shared__ float sh_new[8][NF + 1];
    __shared__ float sg[8][NF];

    const int tid  = threadIdx.x;
    const int b    = blockIdx.x >> 5;
    const int oct  = blockIdx.x & 31;
    const int n0l  = 8 * oct;
    const size_t n0 = (size_t)b * NN + n0l;
    const int w    = tid >> 6;
    const int lane = tid & 63;
    const int c    = lane & 15;
    const int g    = lane >> 4;

    // ---- stage all weights + x ----
    sWs[tid] = We1_l[tid];
    sWd[tid] = We1_l[256 + tid];
    sWh1s[tid]       = Wh1_l[tid];
    sWh1s[256 + tid] = Wh1_l[256 + tid];
    {
        const int f = tid >> 4, kk = tid & 15;
        sWa[kk * NF + f] = We1_n[tid];
        sWb[kk * NF + f] = We1_n[256 + tid];
        if (tid < NF) sbe1n[tid] = be1_n[tid];
    }
    {   // x0 padded stride-4 from xs stride-3; w slot = |x|^2
        const size_t base = ((size_t)b * NN + tid) * 3;
        const float x0v = xs[base + 0], x1v = xs[base + 1], x2v = xs[base + 2];
        sX[tid * 4 + 0] = x0v;
        sX[tid * 4 + 1] = x1v;
        sX[tid * 4 + 2] = x2v;
        sX[tid * 4 + 3] = fmaf(x0v, x0v, fmaf(x1v, x1v, x2v * x2v));
    }

    // ---- init: h0 (own octet), su0 (all 256 nodes, f16), sv0 (own octet) ----
    const int nl = tid >> 4, k = tid & 15;
    const float win  = W_in[k];
    const float bin  = b_in[k];
    const float be1k = be1_l[k];
    const int i0 = n0l >> 6;
    const int r0 = (n0l & 63) >> 4;
    const int halfsel = (n0l >> 3) & 1;
    const int own = ((nl >> 3) == halfsel);
#pragma unroll
    for (int i = 0; i < 4; ++i) {
#pragma unroll
        for (int r = 0; r < 4; ++r) {
            const float cq = charges[(size_t)b * NN + 64 * i + 16 * r + nl];
            const float hf = fmaxf(fmaf(cq, win, bin), 0.f);
            sHg[(16 * r + nl) * NF + k] = hf;
            if (i == i0 && r == r0 && own) sH8[nl & 7][k] = hf;
        }
        __syncthreads();
#pragma unroll
        for (int r = 0; r < 4; ++r) {
            const float4* hn = (const float4*)&sHg[(16 * r + nl) * NF];
            const float4 h0q = hn[0], h1q = hn[1], h2q = hn[2], h3q = hn[3];
            float u = 0.f;
#pragma unroll
            for (int q = 0; q < 4; ++q) {
                const float4 hq = (q == 0) ? h0q : (q == 1) ? h1q : (q == 2) ? h2q : h3q;
                u = fmaf(hq.x, sWs[(4 * q + 0) * NF + k], u);
                u = fmaf(hq.y, sWs[(4 * q + 1) * NF + k], u);
                u = fmaf(hq.z, sWs[(4 * q + 2) * NF + k], u);
                u = fmaf(hq.w, sWs[(4 * q + 3) * NF + k], u);
            }
            sSUh[64 * i + 16 * r + nl][k] = (_Float16)u;
            if (i == i0 && r == r0 && own) {
                float v = be1k;
#pragma unroll
                for (int q = 0; q < 4; ++q) {
                    const float4 hq = (q == 0) ? h0q : (q == 1) ? h1q : (q == 2) ? h2q : h3q;
                    v = fmaf(hq.x, sWd[(4 * q + 0) * NF + k], v);
                    v = fmaf(hq.y, sWd[(4 * q + 1) * NF + k], v);
                    v = fmaf(hq.z, sWd[(4 * q + 2) * NF + k], v);
                    v = fmaf(hq.w, sWd[(4 * q + 3) * NF + k], v);
                }
                sSV8[nl & 7][k] = v;
            }
        }
        __syncthreads();
    }

    // ---- layer-0 body (f16 m-path) ----
    const int j0 = n0l + w, j1 = n0l + 4 + w;
    const float4 xj0 = *(const float4*)&sX[4 * j0];   // .w = |xj0|^2
    const float4 xj1 = *(const float4*)&sX[4 * j1];
    half4 afrag;
    afrag.x = (_Float16)We2_l[(4 * g + 0) * NF + c];
    afrag.y = (_Float16)We2_l[(4 * g + 1) * NF + c];
    afrag.z = (_Float16)We2_l[(4 * g + 2) * NF + c];
    afrag.w = (_Float16)We2_l[(4 * g + 3) * NF + c];
    const float4 v40 = *(const float4*)&sSV8[w][4 * g];
    const float4 v41 = *(const float4*)&sSV8[4 + w][4 * g];
    const float4 wr4  = *(const float4*)(We1_l + 512 + 4 * g);
    const float4 be2f = *(const float4*)(be2_l + 4 * g);
    const float4 wxf  = *(const float4*)(Wx_l + 4 * g);
    f32x4 cb;
    cb.x = be2f.x; cb.y = be2f.y; cb.z = be2f.z; cb.w = be2f.w;
    // packed per-dst constants
    h2 wrp01, wrp23, vp001, vp023, vp101, vp123;
    wrp01.x = (_Float16)wr4.x; wrp01.y = (_Float16)wr4.y;
    wrp23.x = (_Float16)wr4.z; wrp23.y = (_Float16)wr4.w;
    vp001.x = (_Float16)v40.x; vp001.y = (_Float16)v40.y;
    vp023.x = (_Float16)v40.z; vp023.y = (_Float16)v40.w;
    vp101.x = (_Float16)v41.x; vp101.y = (_Float16)v41.y;
    vp123.x = (_Float16)v41.z; vp123.y = (_Float16)v41.w;
    h2 hz; hz.x = (_Float16)0.f; hz.y = (_Float16)0.f;
    const float m20x = -2.f * xj0.x, m20y = -2.f * xj0.y, m20z = -2.f * xj0.z;
    const float m21x = -2.f * xj1.x, m21y = -2.f * xj1.y, m21z = -2.f * xj1.z;

    float Sw0 = 0.f, Swx0 = 0.f, Swy0 = 0.f, Swz0 = 0.f;
    float Sw1 = 0.f, Swx1 = 0.f, Swy1 = 0.f, Swz1 = 0.f;
    float g00 = 0.f, g01 = 0.f, g02 = 0.f, g03 = 0.f;
    float g10 = 0.f, g11 = 0.f, g12 = 0.f, g13 = 0.f;

    const _Float16* su_lh = &sSUh[c][4 * g];   // +320 halves per tile (16 rows x 20)
    const float* x_l  = &sX[4 * c];

#pragma unroll 2
    for (int t = 0; t < 16; ++t) {
        const half4 uh = *(const half4*)(su_lh + 320 * t);
        const float4 xs4 = *(const float4*)(x_l + 64 * t);
        h2 u01, u23;
        u01.x = uh.x; u01.y = uh.y; u23.x = uh.z; u23.y = uh.w;
        const int s = 16 * t + c;
        {
            const float r2 = fmaf(m20x, xs4.x, fmaf(m20y, xs4.y, fmaf(m20z, xs4.z, xs4.w + xj0.w)));
            const _Float16 r2h = (_Float16)r2;
            h2 r2v; r2v.x = r2h; r2v.y = r2h;
            const h2 m01 = __builtin_elementwise_max(r2v * wrp01 + (u01 + vp001), hz);
            const h2 m23 = __builtin_elementwise_max(r2v * wrp23 + (u23 + vp023), hz);
            half4 bfrag;
            bfrag.x = m01.x; bfrag.y = m01.y; bfrag.z = m23.x; bfrag.w = m23.y;
            const f32x4 acc = __builtin_amdgcn_mfma_f32_16x16x16f16(afrag, bfrag, cb, 0, 0, 0);
            const float e0 = fmaxf(acc.x, 0.f);
            const float e1 = fmaxf(acc.y, 0.f);
            const float e2 = fmaxf(acc.z, 0.f);
            const float e3 = fmaxf(acc.w, 0.f);
            float wp = e0 * wxf.x;
            wp = fmaf(e1, wxf.y, wp);
            wp = fmaf(e2, wxf.z, wp);
            wp = fmaf(e3, wxf.w, wp);
            const float gsel = (s != j0) ? 1.f : 0.f;
            g00 = fmaf(e0, gsel, g00);
            g01 = fmaf(e1, gsel, g01);
            g02 = fmaf(e2, gsel, g02);
            g03 = fmaf(e3, gsel, g03);
            Sw0 += wp;
            Swx0 = fmaf(wp, xs4.x, Swx0);
            Swy0 = fmaf(wp, xs4.y, Swy0);
            Swz0 = fmaf(wp, xs4.z, Swz0);
        }
        {
            const float r2 = fmaf(m21x, xs4.x, fmaf(m21y, xs4.y, fmaf(m21z, xs4.z, xs4.w + xj1.w)));
            const _Float16 r2h = (_Float16)r2;
            h2 r2v; r2v.x = r2h; r2v.y = r2h;
            const h2 m01 = __builtin_elementwise_max(r2v * wrp01 + (u01 + vp101), hz);
            const h2 m23 = __builtin_elementwise_max(r2v * wrp23 + (u23 + vp123), hz);
            half4 bfrag;
            bfrag.x = m01.x; bfrag.y = m01.y; bfrag.z = m23.x; bfrag.w = m23.y;
            const f32x4 acc = __builtin_amdgcn_mfma_f32_16x16x16f16(afrag, bfrag, cb, 0, 0, 0);
            const float e0 = fmaxf(acc.x, 0.f);
            const float e1 = fmaxf(acc.y, 0.f);
            const float e2 = fmaxf(acc.z, 0.f);
            const float e3 = fmaxf(acc.w, 0.f);
            float wp = e0 * wxf.x;
            wp = fmaf(e1, wxf.y, wp);
            wp = fmaf(e2, wxf.z, wp);
            wp = fmaf(e3, wxf.w, wp);
            const float gsel = (s != j1) ? 1.f : 0.f;
            g10 = fmaf(e0, gsel, g10);
            g11 = fmaf(e1, gsel, g11);
            g12 = fmaf(e2, gsel, g12);
            g13 = fmaf(e3, gsel, g13);
            Sw1 += wp;
            Swx1 = fmaf(wp, xs4.x, Swx1);
            Swy1 = fmaf(wp, xs4.y, Swy1);
            Swz1 = fmaf(wp, xs4.z, Swz1);
        }
    }

#pragma unroll
    for (int off = 1; off < 64; off <<= 1) {
        Sw0  += __shfl_xor(Sw0,  off, 64);  Sw1  += __shfl_xor(Sw1,  off, 64);
        Swx0 += __shfl_xor(Swx0, off, 64);  Swx1 += __shfl_xor(Swx1, off, 64);
        Swy0 += __shfl_xor(Swy0, off, 64);  Swy1 += __shfl_xor(Swy1, off, 64);
        Swz0 += __shfl_xor(Swz0, off, 64);  Swz1 += __shfl_xor(Swz1, off, 64);
    }
#pragma unroll
    for (int off = 1; off < 16; off <<= 1) {
        g00 += __shfl_xor(g00, off, 64);  g10 += __shfl_xor(g10, off, 64);
        g01 += __shfl_xor(g01, off, 64);  g11 += __shfl_xor(g11, off, 64);
        g02 += __shfl_xor(g02, off, 64);  g12 += __shfl_xor(g12, off, 64);
        g03 += __shfl_xor(g03, off, 64);  g13 += __shfl_xor(g13, off, 64);
    }
    if ((lane & 15) == 0) {
        *(float4*)&sg[w][4 * g]     = make_float4(g00, g01, g02, g03);
        *(float4*)&sg[w + 4][4 * g] = make_float4(g10, g11, g12, g13);
    }
    __syncthreads();

    const int is0 = (lane < 16);
    const int is1 = (lane >= 32 && lane < 48);
    if (is0 || is1) {
        const int f = lane & 15;
        const int slot = is0 ? w : (w + 4);
        const int jm   = is0 ? j0 : j1;
        const float SwS = is0 ? Sw0  : Sw1;
        const float SxS = is0 ? Swx0 : Swx1;
        const float SyS = is0 ? Swy0 : Swy1;
        const float SzS = is0 ? Swz0 : Swz1;
        const float4 xjm = is0 ? xj0 : xj1;
        const size_t nj = (size_t)b * NN + jm;
        float hd = bh1_l[f];
        float hv = 0.f;
#pragma unroll
        for (int kk = 0; kk < NF; ++kk) {
            const float hjk = sH8[slot][kk];
            hd = fmaf(hjk, sWh1s[kk * NF + f], hd);
            hv = fmaf(hjk, W_v[kk], hv);
        }
#pragma unroll
        for (int kk = 0; kk < NF; ++kk) {
            hd = fmaf(sg[slot][kk], sWh1s[(NF + kk) * NF + f], hd);
        }
        const float hnew = sH8[slot][f] + fmaxf(hd, 0.f);
        sh_new[slot][f] = hnew;
        h_out[nj * NF + f] = hnew;
        if (f < 3) {
            const float xc = (f == 0) ? xjm.x : ((f == 1) ? xjm.y : xjm.z);
            const float Sc = (f == 0) ? SxS  : ((f == 1) ? SyS  : SzS);
            const float agg = (SwS * xc - Sc) * (1.f / 255.f);
            const float xnew = xc + agg + vs[nj * 3 + f] * hv;
            x_out[nj * 4 + f] = xnew;
        }
        if (f == 3) x_out[nj * 4 + 3] = 0.f;
    }

    __syncthreads();
    if (tid < 128) {
        const int jd = tid >> 4, kk = tid & 15;
        float u = 0.f, v = sbe1n[kk];
#pragma unroll
        for (int f = 0; f < NF; ++f) {
            const float hf = sh_new[jd][f];
            u = fmaf(hf, sWa[kk * NF + f], u);
            v = fmaf(hf, sWb[kk * NF + f], v);
        }
        su_out[(n0 + jd) * NF + kk] = u;
        sv_out[(n0 + jd) * NF + kk] = v;
    }
}

// R22 layer kernel: R14/R16 structure with the packed-f16 m-path.
__global__ __launch_bounds__(256)
void layer_kernel(const float* __restrict__ x_in, const float* __restrict__ h_in,
                  const float* __restrict__ su_in, const float* __restrict__ sv_in,
                  float* __restrict__ x_out, float* __restrict__ h_out,
                  float* __restrict__ su_out, float* __restrict__ sv_out,
                  const float* __restrict__ vs, const float* __restrict__ Wv_l,
                  const float* __restrict__ We1_l, const float* __restrict__ We2_l,
                  const float* __restrict__ be2_l, const float* __restrict__ Wx_l,
                  const float* __restrict__ Wh1_l, const float* __restrict__ bh1_l,
                  const float* __restrict__ We1_n, const float* __restrict__ be1_n,
                  int final_layer) {
    __shared__ __align__(16) _Float16 sSUh[NN][20];  // 10 KB f16 su, padded rows
    __shared__ __align__(16) float sX[NN * 4];       // 4 KB, w = |x|^2
    __shared__ float sWh1s[512];
    __shared__ float sWa[256];
    __shared__ float sWb[256];
    __shared__ float sbe1n[NF];
    __shared__ float sh_new[8][NF + 1];
    __shared__ float sg[8][NF];

    const int tid  = threadIdx.x;
    const int b    = blockIdx.x >> 5;
    const int oct  = blockIdx.x & 31;
    const int n0l  = 8 * oct;
    const size_t n0 = (size_t)b * NN + n0l;
    const int w    = tid >> 6;
    const int lane = tid & 63;
    const int c    = lane & 15;
    const int g    = lane >> 4;

    sWh1s[tid]       = Wh1_l[tid];
    sWh1s[256 + tid] = Wh1_l[256 + tid];
    if (!final_layer) {
        const int f = tid >> 4, k = tid & 15;
        sWa[k * NF + f] = We1_n[tid];
        sWb[k * NF + f] = We1_n[256 + tid];
        if (tid < NF) sbe1n[tid] = be1_n[tid];
    }
    {   // stage su -> f16 padded LDS; x with |x|^2 in w
        const float4* gsu = (const float4*)(su_in + (size_t)b * NN * NF);
#pragma unroll
        for (int i = 0; i < 4; ++i) {
            const int idx = tid + 256 * i;
            const float4 u = gsu[idx];
            const int node = idx >> 2, k0 = (idx & 3) * 4;
            half4 p;
            p.x = (_Float16)u.x; p.y = (_Float16)u.y;
            p.z = (_Float16)u.z; p.w = (_Float16)u.w;
            *(half4*)&sSUh[node][k0] = p;
        }
        const float4* gx = (const float4*)(x_in + (size_t)b * NN * 4);
        float4 xv = gx[tid];
        xv.w = fmaf(xv.x, xv.x, fmaf(xv.y, xv.y, xv.z * xv.z));
        ((float4*)sX)[tid] = xv;
    }
    __syncthreads();

    const int j0 = n0l + w, j1 = n0l + 4 + w;
    const float4 xj0 = *(const float4*)&sX[4 * j0];
    const float4 xj1 = *(const float4*)&sX[4 * j1];
    half4 afrag;
    afrag.x = (_Float16)We2_l[(4 * g + 0) * NF + c];
    afrag.y = (_Float16)We2_l[(4 * g + 1) * NF + c];
    afrag.z = (_Float16)We2_l[(4 * g + 2) * NF + c];
    afrag.w = (_Float16)We2_l[(4 * g + 3) * NF + c];
    const float4 v40  = *(const float4*)(sv_in + ((size_t)b * NN + j0) * NF + 4 * g);
    const float4 v41  = *(const float4*)(sv_in + ((size_t)b * NN + j1) * NF + 4 * g);
    const float4 wr4  = *(const float4*)(We1_l + 512 + 4 * g);
    const float4 be2f = *(const float4*)(be2_l + 4 * g);
    const float4 wxf  = *(const float4*)(Wx_l + 4 * g);
    f32x4 cb;
    cb.x = be2f.x; cb.y = be2f.y; cb.z = be2f.z; cb.w = be2f.w;
    h2 wrp01, wrp23, vp001, vp023, vp101, vp123;
    wrp01.x = (_Float16)wr4.x; wrp01.y = (_Float16)wr4.y;
    wrp23.x = (_Float16)wr4.z; wrp23.y = (_Float16)wr4.w;
    vp001.x = (_Float16)v40.x; vp001.y = (_Float16)v40.y;
    vp023.x = (_Float16)v40.z; vp023.y = (_Float16)v40.w;
    vp101.x = (_Float16)v41.x; vp101.y = (_Float16)v41.y;
    vp123.x = (_Float16)v41.z; vp123.y = (_Float16)v41.w;
    h2 hz; hz.x = (_Float16)0.f; hz.y = (_Float16)0.f;
    const float m20x = -2.f * xj0.x, m20y = -2.f * xj0.y, m20z = -2.f * xj0.z;
    const float m21x = -2.f * xj1.x, m21y = -2.f * xj1.y, m21z = -2.f * xj1.z;

    float Sw0 = 0.f, Swx0 = 0.f, Swy0 = 0.f, Swz0 = 0.f;
    float Sw1 = 0.f, Swx1 = 0.f, Swy1 = 0.f, Swz1 = 0.f;
    float g00 = 0.f, g01 = 0.f, g02 = 0.f, g03 = 0.f;
    float g10 = 0.f, g11 = 0.f, g12 = 0.f, g13 = 0.f;

    const _Float16* su_lh = &sSUh[c][4 * g];   // +320 halves per tile
    const float* x_l  = &sX[4 * c];

#pragma unroll 2
    for (int t = 0; t < 16; ++t) {
        const half4 uh = *(const half4*)(su_lh + 320 * t);
        const float4 xs4 = *(const float4*)(x_l + 64 * t);
        h2 u01, u23;
        u01.x = uh.x; u01.y = uh.y; u23.x = uh.z; u23.y = uh.w;
        const int s = 16 * t + c;
        {
            const float r2 = fmaf(m20x, xs4.x, fmaf(m20y, xs4.y, fmaf(m20z, xs4.z, xs4.w + xj0.w)));
            const _Float16 r2h = (_Float16)r2;
            h2 r2v; r2v.x = r2h; r2v.y = r2h;
            const h2 m01 = __builtin_elementwise_max(r2v * wrp01 + (u01 + vp001), hz);
            const h2 m23 = __builtin_elementwise_max(r2v * wrp23 + (u23 + vp023), hz);
            half4 bfrag;
            bfrag.x = m01.x; bfrag.y = m01.y; bfrag.z = m23.x; bfrag.w = m23.y;
            const f32x4 acc = __builtin_amdgcn_mfma_f32_16x16x16f16(afrag, bfrag, cb, 0, 0, 0);
            const float e0 = fmaxf(acc.x, 0.f);
            const float e1 = fmaxf(acc.y, 0.f);
            const float e2 = fmaxf(acc.z, 0.f);
            const float e3 = fmaxf(acc.w, 0.f);
            float wp = e0 * wxf.x;
            wp = fmaf(e1, wxf.y, wp);
            wp = fmaf(e2, wxf.z, wp);
            wp = fmaf(e3, wxf.w, wp);
            const float gsel = (s != j0) ? 1.f : 0.f;
            g00 = fmaf(e0, gsel, g00);
            g01 = fmaf(e1, gsel, g01);
            g02 = fmaf(e2, gsel, g02);
            g03 = fmaf(e3, gsel, g03);
            Sw0 += wp;
            Swx0 = fmaf(wp, xs4.x, Swx0);
            Swy0 = fmaf(wp, xs4.y, Swy0);
            Swz0 = fmaf(wp, xs4.z, Swz0);
        }
        {
            const float r2 = fmaf(m21x, xs4.x, fmaf(m21y, xs4.y, fmaf(m21z, xs4.z, xs4.w + xj1.w)));
            const _Float16 r2h = (_Float16)r2;
            h2 r2v; r2v.x = r2h; r2v.y = r2h;
            const h2 m01 = __builtin_elementwise_max(r2v * wrp01 + (u01 + vp101), hz);
            const h2 m23 = __builtin_elementwise_max(r2v * wrp23 + (u23 + vp123), hz);
            half4 bfrag;
            bfrag.x = m01.x; bfrag.y = m01.y; bfrag.z = m23.x; bfrag.w = m23.y;
            const f32x4 acc = __builtin_amdgcn_mfma_f32_16x16x16f16(afrag, bfrag, cb, 0, 0, 0);
            const float e0 = fmaxf(acc.x, 0.f);
            const float e1 = fmaxf(acc.y, 0.f);
            const float e2 = fmaxf(acc.z, 0.f);
            const float e3 = fmaxf(acc.w, 0.f);
            float wp = e0 * wxf.x;
            wp = fmaf(e1, wxf.y, wp);
            wp = fmaf(e2, wxf.z, wp);
            wp = fmaf(e3, wxf.w, wp);
            const float gsel = (s != j1) ? 1.f : 0.f;
            g10 = fmaf(e0, gsel, g10);
            g11 = fmaf(e1, gsel, g11);
            g12 = fmaf(e2, gsel, g12);
            g13 = fmaf(e3, gsel, g13);
            Sw1 += wp;
            Swx1 = fmaf(wp, xs4.x, Swx1);
            Swy1 = fmaf(wp, xs4.y, Swy1);
            Swz1 = fmaf(wp, xs4.z, Swz1);
        }
    }

#pragma unroll
    for (int off = 1; off < 64; off <<= 1) {
        Sw0  += __shfl_xor(Sw0,  off, 64);  Sw1  += __shfl_xor(Sw1,  off, 64);
        Swx0 += __shfl_xor(Swx0, off, 64);  Swx1 += __shfl_xor(Swx1, off, 64);
        Swy0 += __shfl_xor(Swy0, off, 64);  Swy1 += __shfl_xor(Swy1, off, 64);
        Swz0 += __shfl_xor(Swz0, off, 64);  Swz1 += __shfl_xor(Swz1, off, 64);
    }
#pragma unroll
    for (int off = 1; off < 16; off <<= 1) {
        g00 += __shfl_xor(g00, off, 64);  g10 += __shfl_xor(g10, off, 64);
        g01 += __shfl_xor(g01, off, 64);  g11 += __shfl_xor(g11, off, 64);
        g02 += __shfl_xor(g02, off, 64);  g12 += __shfl_xor(g12, off, 64);
        g03 += __shfl_xor(g03, off, 64);  g13 += __shfl_xor(g13, off, 64);
    }
    if ((lane & 15) == 0) {
        *(float4*)&sg[w][4 * g]     = make_float4(g00, g01, g02, g03);
        *(float4*)&sg[w + 4][4 * g] = make_float4(g10, g11, g12, g13);
    }
    __syncthreads();

    const int is0 = (lane < 16);
    const int is1 = (lane >= 32 && lane < 48);
    if (is0 || is1) {
        const int f = lane & 15;
        const int slot = is0 ? w : (w + 4);
        const int jm   = is0 ? j0 : j1;
        const float SwS = is0 ? Sw0  : Sw1;
        const float SxS = is0 ? Swx0 : Swx1;
        const float SyS = is0 ? Swy0 : Swy1;
        const float SzS = is0 ? Swz0 : Swz1;
        const float4 xjm = is0 ? xj0 : xj1;
        const size_t nj = (size_t)b * NN + jm;
        float hd = bh1_l[f];
        float hv = 0.f;
#pragma unroll
        for (int k = 0; k < NF; ++k) {
            const float hjk = h_in[nj * NF + k];
            hd = fmaf(hjk, sWh1s[k * NF + f], hd);
            hv = fmaf(hjk, Wv_l[k], hv);
        }
#pragma unroll
        for (int k = 0; k < NF; ++k) {
            hd = fmaf(sg[slot][k], sWh1s[(NF + k) * NF + f], hd);
        }
        const float hnew = h_in[nj * NF + f] + fmaxf(hd, 0.f);
        sh_new[slot][f] = hnew;
        if (!final_layer) h_out[nj * NF + f] = hnew;
        if (f < 3) {
            const float xc = (f == 0) ? xjm.x : ((f == 1) ? xjm.y : xjm.z);
            const float Sc = (f == 0) ? SxS  : ((f == 1) ? SyS  : SzS);
            const float agg = (SwS * xc - Sc) * (1.f / 255.f);
            const float xnew = xc + agg + vs[nj * 3 + f] * hv;
            if (final_layer) x_out[nj * 3 + f] = xnew;
            else             x_out[nj * 4 + f] = xnew;
        }
        if (!final_layer && f == 3) x_out[nj * 4 + 3] = 0.f;
    }

    if (!final_layer) {
        __syncthreads();
        if (tid < 128) {
            const int jd = tid >> 4, k = tid & 15;
            float u = 0.f, v = sbe1n[k];
#pragma unroll
            for (int f = 0; f < NF; ++f) {
                const float hf = sh_new[jd][f];
                u = fmaf(hf, sWa[k * NF + f], u);
                v = fmaf(hf, sWb[k * NF + f], v);
            }
            su_out[(n0 + jd) * NF + k] = u;
            sv_out[(n0 + jd) * NF + k] = v;
        }
    }
}

extern "C" void kernel_launch(void* const* d_in, const int* in_sizes, int n_in,
                              void* d_out, int out_size, void* d_ws, size_t ws_size,
                              hipStream_t stream) {
    const float* xs      = (const float*)d_in[0];
    const float* vs      = (const float*)d_in[1];
    const float* charges = (const float*)d_in[2];
    const float* W_in    = (const float*)d_in[3];
    const float* b_in    = (const float*)d_in[4];
    const float* W_v     = (const float*)d_in[5];
    const float* We1     = (const float*)d_in[6];
    const float* be1     = (const float*)d_in[7];
    const float* We2     = (const float*)d_in[8];
    const float* be2     = (const float*)d_in[9];
    const float* Wx      = (const float*)d_in[10];
    const float* Wh1     = (const float*)d_in[11];
    const float* bh1     = (const float*)d_in[12];
    // d_in[13]=src, d_in[14]=dst: fully-connected pattern, computed analytically.

    float* ws = (float*)d_ws;
    float* xA  = ws + XA_OFF;
    float* xB  = ws + XB_OFF;
    float* hA  = ws + HA_OFF;
    float* hB  = ws + HB_OFF;
    float* suA = ws + SUA_OFF;
    float* svA = ws + SVA_OFF;
    float* suB = ws + SUB_OFF;
    float* svB = ws + SVB_OFF;
    float* out = (float*)d_out;

    // L0 (init fused): writes xA, hA, suA, svA
    hipLaunchKernelGGL(layer0_kernel, dim3(1024), dim3(256), 0, stream,
                       xs, vs, charges, W_in, b_in,
                       W_v + 0 * 16, We1 + 0 * 528, be1 + 0 * 16, We2 + 0 * 256,
                       be2 + 0 * 16, Wx + 0 * 16, Wh1 + 0 * 512, bh1 + 0 * 16,
                       We1 + 1 * 528, be1 + 1 * 16,
                       xA, hA, suA, svA);
    // L1
    hipLaunchKernelGGL(layer_kernel, dim3(1024), dim3(256), 0, stream,
                       xA, hA, suA, svA, xB, hB, suB, svB,
                       vs, W_v + 1 * 16, We1 + 1 * 528, We2 + 1 * 256,
                       be2 + 1 * 16, Wx + 1 * 16, Wh1 + 1 * 512, bh1 + 1 * 16,
                       We1 + 2 * 528, be1 + 2 * 16, 0);
    // L2 (final)
    hipLaunchKernelGGL(layer_kernel, dim3(1024), dim3(256), 0, stream,
                       xB, hB, suB, svB, out, hA, suA, svA,
                       vs, W_v + 2 * 16, We1 + 2 * 528, We2 + 2 * 256,
                       be2 + 2 * 16, Wx + 2 * 16, Wh1 + 2 * 512, bh1 + 2 * 16,
                       We1 + 2 * 528, be1 + 2 * 16, 1);
}

// Round 11
// 125.630 us; speedup vs baseline: 1.3029x; 1.0367x over previous
//
#include <hip/hip_runtime.h>

#define NN 256
#define NF 16

typedef _Float16 half4 __attribute__((ext_vector_type(4)));
typedef _Float16 h2 __attribute__((ext_vector_type(2)));
typedef __fp16 fh2 __attribute__((ext_vector_type(2)));
typedef float f32x4 __attribute__((ext_vector_type(4)));

#define CVTPK(a, b) __builtin_bit_cast(h2, __builtin_amdgcn_cvt_pkrtz((a), (b)))
#define FDOT2(a, b, c) __builtin_amdgcn_fdot2(__builtin_bit_cast(fh2, (a)), __builtin_bit_cast(fh2, (b)), (c), false)

// ws layout (floats): ping-pong x/h/su/sv
#define XA_OFF 0
#define XB_OFF 32768
#define HA_OFF 65536
#define HB_OFF 196608
#define SUA_OFF 327680
#define SVA_OFF 458752
#define SUB_OFF 589824
#define SVB_OFF 720896

// R25 == R23 resubmitted verbatim (R24 bench was an infra failure; kernel
// never ran). Packed post-path: R22 (f16 m-path) gained 1.6us -> post-MFMA
// path dominates in-loop issue. Cuts: e->h2 via cvt_pkrtz+pk_max; wp via
// v_dot2_f32_f16 (declared risk: fdot2 availability on gfx950); g as h2
// pk_fma with bit-pattern gsel 0x3C003C00 (halves the 16-lane reduction);
// r2 broadcast via cvt_pkrtz(r2,r2). ~-25% in-loop issue. g in f16 over
// 255 terms: absmax 2.0 -> expect 2-4, threshold 9.6.
__global__ __launch_bounds__(256)
void layer0_kernel(const float* __restrict__ xs, const float* __restrict__ vs,
                   const float* __restrict__ charges,
                   const float* __restrict__ W_in, const float* __restrict__ b_in,
                   const float* __restrict__ W_v, const float* __restrict__ We1_l,
                   const float* __restrict__ be1_l, const float* __restrict__ We2_l,
                   const float* __restrict__ be2_l, const float* __restrict__ Wx_l,
                   const float* __restrict__ Wh1_l, const float* __restrict__ bh1_l,
                   const float* __restrict__ We1_n, const float* __restrict__ be1_n,
                   float* __restrict__ x_out, float* __restrict__ h_out,
                   float* __restrict__ su_out, float* __restrict__ sv_out) {
    __shared__ __align__(16) _Float16 sSUh[NN][20];  // 10 KB: su0 as f16, padded
    __shared__ __align__(16) float sX[NN * 4];       // 4 KB: x0, w = |x|^2
    __shared__ __align__(16) float sHg[64 * NF];     // 4 KB: init scratch
    __shared__ float sWs[256], sWd[256];             // L0 We1 src/dst
    __shared__ __align__(16) float sSV8[8][NF];      // own-octet sv0
    __shared__ __align__(16) float sH8[8][NF + 1];   // own-octet h0
    __shared__ float sWh1s[512];
    __shared__ float sWa[256], sWb[256];             // next-layer We1^T
    __shared__ float sbe1n[NF];
    __shared__ float sh_new[8][NF + 1];
    __shared__ float sg[8][NF];

    const int tid  = threadIdx.x;
    const int b    = blockIdx.x >> 5;
    const int oct  = blockIdx.x & 31;
    const int n0l  = 8 * oct;
    const size_t n0 = (size_t)b * NN + n0l;
    const int w    = tid >> 6;
    const int lane = tid & 63;
    const int c    = lane & 15;
    const int g    = lane >> 4;

    // ---- stage all weights + x ----
    sWs[tid] = We1_l[tid];
    sWd[tid] = We1_l[256 + tid];
    sWh1s[tid]       = Wh1_l[tid];
    sWh1s[256 + tid] = Wh1_l[256 + tid];
    {
        const int f = tid >> 4, kk = tid & 15;
        sWa[kk * NF + f] = We1_n[tid];
        sWb[kk * NF + f] = We1_n[256 + tid];
        if (tid < NF) sbe1n[tid] = be1_n[tid];
    }
    {   // x0 padded stride-4 from xs stride-3; w slot = |x|^2
        const size_t base = ((size_t)b * NN + tid) * 3;
        const float x0v = xs[base + 0], x1v = xs[base + 1], x2v = xs[base + 2];
        sX[tid * 4 + 0] = x0v;
        sX[tid * 4 + 1] = x1v;
        sX[tid * 4 + 2] = x2v;
        sX[tid * 4 + 3] = fmaf(x0v, x0v, fmaf(x1v, x1v, x2v * x2v));
    }

    // ---- init: h0 (own octet), su0 (all 256 nodes, f16), sv0 (own octet) ----
    const int nl = tid >> 4, k = tid & 15;
    const float win  = W_in[k];
    const float bin  = b_in[k];
    const float be1k = be1_l[k];
    const int i0 = n0l >> 6;
    const int r0 = (n0l & 63) >> 4;
    const int halfsel = (n0l >> 3) & 1;
    const int own = ((nl >> 3) == halfsel);
#pragma unroll
    for (int i = 0; i < 4; ++i) {
#pragma unroll
        for (int r = 0; r < 4; ++r) {
            const float cq = charges[(size_t)b * NN + 64 * i + 16 * r + nl];
            const float hf = fmaxf(fmaf(cq, win, bin), 0.f);
            sHg[(16 * r + nl) * NF + k] = hf;
            if (i == i0 && r == r0 && own) sH8[nl & 7][k] = hf;
        }
        __syncthreads();
#pragma unroll
        for (int r = 0; r < 4; ++r) {
            const float4* hn = (const float4*)&sHg[(16 * r + nl) * NF];
            const float4 h0q = hn[0], h1q = hn[1], h2q = hn[2], h3q = hn[3];
            float u = 0.f;
#pragma unroll
            for (int q = 0; q < 4; ++q) {
                const float4 hq = (q == 0) ? h0q : (q == 1) ? h1q : (q == 2) ? h2q : h3q;
                u = fmaf(hq.x, sWs[(4 * q + 0) * NF + k], u);
                u = fmaf(hq.y, sWs[(4 * q + 1) * NF + k], u);
                u = fmaf(hq.z, sWs[(4 * q + 2) * NF + k], u);
                u = fmaf(hq.w, sWs[(4 * q + 3) * NF + k], u);
            }
            sSUh[64 * i + 16 * r + nl][k] = (_Float16)u;
            if (i == i0 && r == r0 && own) {
                float v = be1k;
#pragma unroll
                for (int q = 0; q < 4; ++q) {
                    const float4 hq = (q == 0) ? h0q : (q == 1) ? h1q : (q == 2) ? h2q : h3q;
                    v = fmaf(hq.x, sWd[(4 * q + 0) * NF + k], v);
                    v = fmaf(hq.y, sWd[(4 * q + 1) * NF + k], v);
                    v = fmaf(hq.z, sWd[(4 * q + 2) * NF + k], v);
                    v = fmaf(hq.w, sWd[(4 * q + 3) * NF + k], v);
                }
                sSV8[nl & 7][k] = v;
            }
        }
        __syncthreads();
    }

    // ---- layer-0 body (f16 m-path + packed post-path) ----
    const int j0 = n0l + w, j1 = n0l + 4 + w;
    const float4 xj0 = *(const float4*)&sX[4 * j0];
    const float4 xj1 = *(const float4*)&sX[4 * j1];
    half4 afrag;
    afrag.x = (_Float16)We2_l[(4 * g + 0) * NF + c];
    afrag.y = (_Float16)We2_l[(4 * g + 1) * NF + c];
    afrag.z = (_Float16)We2_l[(4 * g + 2) * NF + c];
    afrag.w = (_Float16)We2_l[(4 * g + 3) * NF + c];
    const float4 v40 = *(const float4*)&sSV8[w][4 * g];
    const float4 v41 = *(const float4*)&sSV8[4 + w][4 * g];
    const float4 wr4  = *(const float4*)(We1_l + 512 + 4 * g);
    const float4 be2f = *(const float4*)(be2_l + 4 * g);
    const float4 wxf  = *(const float4*)(Wx_l + 4 * g);
    f32x4 cb;
    cb.x = be2f.x; cb.y = be2f.y; cb.z = be2f.z; cb.w = be2f.w;
    const h2 wrp01 = CVTPK(wr4.x, wr4.y), wrp23 = CVTPK(wr4.z, wr4.w);
    const h2 vp001 = CVTPK(v40.x, v40.y), vp023 = CVTPK(v40.z, v40.w);
    const h2 vp101 = CVTPK(v41.x, v41.y), vp123 = CVTPK(v41.z, v41.w);
    const h2 wxp01 = CVTPK(wxf.x, wxf.y), wxp23 = CVTPK(wxf.z, wxf.w);
    h2 hz; hz.x = (_Float16)0.f; hz.y = (_Float16)0.f;
    const float m20x = -2.f * xj0.x, m20y = -2.f * xj0.y, m20z = -2.f * xj0.z;
    const float m21x = -2.f * xj1.x, m21y = -2.f * xj1.y, m21z = -2.f * xj1.z;

    float Sw0 = 0.f, Swx0 = 0.f, Swy0 = 0.f, Swz0 = 0.f;
    float Sw1 = 0.f, Swx1 = 0.f, Swy1 = 0.f, Swz1 = 0.f;
    h2 g01_0 = hz, g23_0 = hz, g01_1 = hz, g23_1 = hz;

    const _Float16* su_lh = &sSUh[c][4 * g];
    const float* x_l  = &sX[4 * c];

#pragma unroll 2
    for (int t = 0; t < 16; ++t) {
        const half4 uh = *(const half4*)(su_lh + 320 * t);
        const float4 xs4 = *(const float4*)(x_l + 64 * t);
        h2 u01, u23;
        u01.x = uh.x; u01.y = uh.y; u23.x = uh.z; u23.y = uh.w;
        const int s = 16 * t + c;
        {
            const float r2 = fmaf(m20x, xs4.x, fmaf(m20y, xs4.y, fmaf(m20z, xs4.z, xs4.w + xj0.w)));
            const h2 r2v = CVTPK(r2, r2);
            const h2 m01 = __builtin_elementwise_max(r2v * wrp01 + (u01 + vp001), hz);
            const h2 m23 = __builtin_elementwise_max(r2v * wrp23 + (u23 + vp023), hz);
            half4 bfrag;
            bfrag.x = m01.x; bfrag.y = m01.y; bfrag.z = m23.x; bfrag.w = m23.y;
            const f32x4 acc = __builtin_amdgcn_mfma_f32_16x16x16f16(afrag, bfrag, cb, 0, 0, 0);
            const h2 e01 = __builtin_elementwise_max(CVTPK(acc.x, acc.y), hz);
            const h2 e23 = __builtin_elementwise_max(CVTPK(acc.z, acc.w), hz);
            const float wp = FDOT2(e01, wxp01, FDOT2(e23, wxp23, 0.f));
            const unsigned gm = (s != j0) ? 0x3C003C00u : 0u;
            const h2 gu = __builtin_bit_cast(h2, gm);
            g01_0 = e01 * gu + g01_0;
            g23_0 = e23 * gu + g23_0;
            Sw0 += wp;
            Swx0 = fmaf(wp, xs4.x, Swx0);
            Swy0 = fmaf(wp, xs4.y, Swy0);
            Swz0 = fmaf(wp, xs4.z, Swz0);
        }
        {
            const float r2 = fmaf(m21x, xs4.x, fmaf(m21y, xs4.y, fmaf(m21z, xs4.z, xs4.w + xj1.w)));
            const h2 r2v = CVTPK(r2, r2);
            const h2 m01 = __builtin_elementwise_max(r2v * wrp01 + (u01 + vp101), hz);
            const h2 m23 = __builtin_elementwise_max(r2v * wrp23 + (u23 + vp123), hz);
            half4 bfrag;
            bfrag.x = m01.x; bfrag.y = m01.y; bfrag.z = m23.x; bfrag.w = m23.y;
            const f32x4 acc = __builtin_amdgcn_mfma_f32_16x16x16f16(afrag, bfrag, cb, 0, 0, 0);
            const h2 e01 = __builtin_elementwise_max(CVTPK(acc.x, acc.y), hz);
            const h2 e23 = __builtin_elementwise_max(CVTPK(acc.z, acc.w), hz);
            const float wp = FDOT2(e01, wxp01, FDOT2(e23, wxp23, 0.f));
            const unsigned gm = (s != j1) ? 0x3C003C00u : 0u;
            const h2 gu = __builtin_bit_cast(h2, gm);
            g01_1 = e01 * gu + g01_1;
            g23_1 = e23 * gu + g23_1;
            Sw1 += wp;
            Swx1 = fmaf(wp, xs4.x, Swx1);
            Swy1 = fmaf(wp, xs4.y, Swy1);
            Swz1 = fmaf(wp, xs4.z, Swz1);
        }
    }

#pragma unroll
    for (int off = 1; off < 64; off <<= 1) {
        Sw0  += __shfl_xor(Sw0,  off, 64);  Sw1  += __shfl_xor(Sw1,  off, 64);
        Swx0 += __shfl_xor(Swx0, off, 64);  Swx1 += __shfl_xor(Swx1, off, 64);
        Swy0 += __shfl_xor(Swy0, off, 64);  Swy1 += __shfl_xor(Swy1, off, 64);
        Swz0 += __shfl_xor(Swz0, off, 64);  Swz1 += __shfl_xor(Swz1, off, 64);
    }
#pragma unroll
    for (int off = 1; off < 16; off <<= 1) {
        g01_0 = g01_0 + __builtin_bit_cast(h2, __shfl_xor(__builtin_bit_cast(int, g01_0), off, 64));
        g23_0 = g23_0 + __builtin_bit_cast(h2, __shfl_xor(__builtin_bit_cast(int, g23_0), off, 64));
        g01_1 = g01_1 + __builtin_bit_cast(h2, __shfl_xor(__builtin_bit_cast(int, g01_1), off, 64));
        g23_1 = g23_1 + __builtin_bit_cast(h2, __shfl_xor(__builtin_bit_cast(int, g23_1), off, 64));
    }
    if ((lane & 15) == 0) {
        *(float4*)&sg[w][4 * g]     = make_float4((float)g01_0.x, (float)g01_0.y,
                                                  (float)g23_0.x, (float)g23_0.y);
        *(float4*)&sg[w + 4][4 * g] = make_float4((float)g01_1.x, (float)g01_1.y,
                                                  (float)g23_1.x, (float)g23_1.y);
    }
    __syncthreads();

    const int is0 = (lane < 16);
    const int is1 = (lane >= 32 && lane < 48);
    if (is0 || is1) {
        const int f = lane & 15;
        const int slot = is0 ? w : (w + 4);
        const int jm   = is0 ? j0 : j1;
        const float SwS = is0 ? Sw0  : Sw1;
        const float SxS = is0 ? Swx0 : Swx1;
        const float SyS = is0 ? Swy0 : Swy1;
        const float SzS = is0 ? Swz0 : Swz1;
        const float4 xjm = is0 ? xj0 : xj1;
        const size_t nj = (size_t)b * NN + jm;
        float hd = bh1_l[f];
        float hv = 0.f;
#pragma unroll
        for (int kk = 0; kk < NF; ++kk) {
            const float hjk = sH8[slot][kk];
            hd = fmaf(hjk, sWh1s[kk * NF + f], hd);
            hv = fmaf(hjk, W_v[kk], hv);
        }
#pragma unroll
        for (int kk = 0; kk < NF; ++kk) {
            hd = fmaf(sg[slot][kk], sWh1s[(NF + kk) * NF + f], hd);
        }
        const float hnew = sH8[slot][f] + fmaxf(hd, 0.f);
        sh_new[slot][f] = hnew;
        h_out[nj * NF + f] = hnew;
        if (f < 3) {
            const float xc = (f == 0) ? xjm.x : ((f == 1) ? xjm.y : xjm.z);
            const float Sc = (f == 0) ? SxS  : ((f == 1) ? SyS  : SzS);
            const float agg = (SwS * xc - Sc) * (1.f / 255.f);
            const float xnew = xc + agg + vs[nj * 3 + f] * hv;
            x_out[nj * 4 + f] = xnew;
        }
        if (f == 3) x_out[nj * 4 + 3] = 0.f;
    }

    __syncthreads();
    if (tid < 128) {
        const int jd = tid >> 4, kk = tid & 15;
        float u = 0.f, v = sbe1n[kk];
#pragma unroll
        for (int f = 0; f < NF; ++f) {
            const float hf = sh_new[jd][f];
            u = fmaf(hf, sWa[kk * NF + f], u);
            v = fmaf(hf, sWb[kk * NF + f], v);
        }
        su_out[(n0 + jd) * NF + kk] = u;
        sv_out[(n0 + jd) * NF + kk] = v;
    }
}

// R25 layer kernel: R22 structure + packed post-path (fdot2 wp, h2 g).
__global__ __launch_bounds__(256)
void layer_kernel(const float* __restrict__ x_in, const float* __restrict__ h_in,
                  const float* __restrict__ su_in, const float* __restrict__ sv_in,
                  float* __restrict__ x_out, float* __restrict__ h_out,
                  float* __restrict__ su_out, float* __restrict__ sv_out,
                  const float* __restrict__ vs, const float* __restrict__ Wv_l,
                  const float* __restrict__ We1_l, const float* __restrict__ We2_l,
                  const float* __restrict__ be2_l, const float* __restrict__ Wx_l,
                  const float* __restrict__ Wh1_l, const float* __restrict__ bh1_l,
                  const float* __restrict__ We1_n, const float* __restrict__ be1_n,
                  int final_layer) {
    __shared__ __align__(16) _Float16 sSUh[NN][20];  // 10 KB f16 su, padded rows
    __shared__ __align__(16) float sX[NN * 4];       // 4 KB, w = |x|^2
    __shared__ float sWh1s[512];
    __shared__ float sWa[256];
    __shared__ float sWb[256];
    __shared__ float sbe1n[NF];
    __shared__ float sh_new[8][NF + 1];
    __shared__ float sg[8][NF];

    const int tid  = threadIdx.x;
    const int b    = blockIdx.x >> 5;
    const int oct  = blockIdx.x & 31;
    const int n0l  = 8 * oct;
    const size_t n0 = (size_t)b * NN + n0l;
    const int w    = tid >> 6;
    const int lane = tid & 63;
    const int c    = lane & 15;
    const int g    = lane >> 4;

    sWh1s[tid]       = Wh1_l[tid];
    sWh1s[256 + tid] = Wh1_l[256 + tid];
    if (!final_layer) {
        const int f = tid >> 4, k = tid & 15;
        sWa[k * NF + f] = We1_n[tid];
        sWb[k * NF + f] = We1_n[256 + tid];
        if (tid < NF) sbe1n[tid] = be1_n[tid];
    }
    {   // stage su -> f16 padded LDS; x with |x|^2 in w
        const float4* gsu = (const float4*)(su_in + (size_t)b * NN * NF);
#pragma unroll
        for (int i = 0; i < 4; ++i) {
            const int idx = tid + 256 * i;
            const float4 u = gsu[idx];
            const int node = idx >> 2, k0 = (idx & 3) * 4;
            half4 p;
            p.x = (_Float16)u.x; p.y = (_Float16)u.y;
            p.z = (_Float16)u.z; p.w = (_Float16)u.w;
            *(half4*)&sSUh[node][k0] = p;
        }
        const float4* gx = (const float4*)(x_in + (size_t)b * NN * 4);
        float4 xv = gx[tid];
        xv.w = fmaf(xv.x, xv.x, fmaf(xv.y, xv.y, xv.z * xv.z));
        ((float4*)sX)[tid] = xv;
    }
    __syncthreads();

    const int j0 = n0l + w, j1 = n0l + 4 + w;
    const float4 xj0 = *(const float4*)&sX[4 * j0];
    const float4 xj1 = *(const float4*)&sX[4 * j1];
    half4 afrag;
    afrag.x = (_Float16)We2_l[(4 * g + 0) * NF + c];
    afrag.y = (_Float16)We2_l[(4 * g + 1) * NF + c];
    afrag.z = (_Float16)We2_l[(4 * g + 2) * NF + c];
    afrag.w = (_Float16)We2_l[(4 * g + 3) * NF + c];
    const float4 v40  = *(const float4*)(sv_in + ((size_t)b * NN + j0) * NF + 4 * g);
    const float4 v41  = *(const float4*)(sv_in + ((size_t)b * NN + j1) * NF + 4 * g);
    const float4 wr4  = *(const float4*)(We1_l + 512 + 4 * g);
    const float4 be2f = *(const float4*)(be2_l + 4 * g);
    const float4 wxf  = *(const float4*)(Wx_l + 4 * g);
    f32x4 cb;
    cb.x = be2f.x; cb.y = be2f.y; cb.z = be2f.z; cb.w = be2f.w;
    const h2 wrp01 = CVTPK(wr4.x, wr4.y), wrp23 = CVTPK(wr4.z, wr4.w);
    const h2 vp001 = CVTPK(v40.x, v40.y), vp023 = CVTPK(v40.z, v40.w);
    const h2 vp101 = CVTPK(v41.x, v41.y), vp123 = CVTPK(v41.z, v41.w);
    const h2 wxp01 = CVTPK(wxf.x, wxf.y), wxp23 = CVTPK(wxf.z, wxf.w);
    h2 hz; hz.x = (_Float16)0.f; hz.y = (_Float16)0.f;
    const float m20x = -2.f * xj0.x, m20y = -2.f * xj0.y, m20z = -2.f * xj0.z;
    const float m21x = -2.f * xj1.x, m21y = -2.f * xj1.y, m21z = -2.f * xj1.z;

    float Sw0 = 0.f, Swx0 = 0.f, Swy0 = 0.f, Swz0 = 0.f;
    float Sw1 = 0.f, Swx1 = 0.f, Swy1 = 0.f, Swz1 = 0.f;
    h2 g01_0 = hz, g23_0 = hz, g01_1 = hz, g23_1 = hz;

    const _Float16* su_lh = &sSUh[c][4 * g];
    const float* x_l  = &sX[4 * c];

#pragma unroll 2
    for (int t = 0; t < 16; ++t) {
        const half4 uh = *(const half4*)(su_lh + 320 * t);
        const float4 xs4 = *(const float4*)(x_l + 64 * t);
        h2 u01, u23;
        u01.x = uh.x; u01.y = uh.y; u23.x = uh.z; u23.y = uh.w;
        const int s = 16 * t + c;
        {
            const float r2 = fmaf(m20x, xs4.x, fmaf(m20y, xs4.y, fmaf(m20z, xs4.z, xs4.w + xj0.w)));
            const h2 r2v = CVTPK(r2, r2);
            const h2 m01 = __builtin_elementwise_max(r2v * wrp01 + (u01 + vp001), hz);
            const h2 m23 = __builtin_elementwise_max(r2v * wrp23 + (u23 + vp023), hz);
            half4 bfrag;
            bfrag.x = m01.x; bfrag.y = m01.y; bfrag.z = m23.x; bfrag.w = m23.y;
            const f32x4 acc = __builtin_amdgcn_mfma_f32_16x16x16f16(afrag, bfrag, cb, 0, 0, 0);
            const h2 e01 = __builtin_elementwise_max(CVTPK(acc.x, acc.y), hz);
            const h2 e23 = __builtin_elementwise_max(CVTPK(acc.z, acc.w), hz);
            const float wp = FDOT2(e01, wxp01, FDOT2(e23, wxp23, 0.f));
            const unsigned gm = (s != j0) ? 0x3C003C00u : 0u;
            const h2 gu = __builtin_bit_cast(h2, gm);
            g01_0 = e01 * gu + g01_0;
            g23_0 = e23 * gu + g23_0;
            Sw0 += wp;
            Swx0 = fmaf(wp, xs4.x, Swx0);
            Swy0 = fmaf(wp, xs4.y, Swy0);
            Swz0 = fmaf(wp, xs4.z, Swz0);
        }
        {
            const float r2 = fmaf(m21x, xs4.x, fmaf(m21y, xs4.y, fmaf(m21z, xs4.z, xs4.w + xj1.w)));
            const h2 r2v = CVTPK(r2, r2);
            const h2 m01 = __builtin_elementwise_max(r2v * wrp01 + (u01 + vp101), hz);
            const h2 m23 = __builtin_elementwise_max(r2v * wrp23 + (u23 + vp123), hz);
            half4 bfrag;
            bfrag.x = m01.x; bfrag.y = m01.y; bfrag.z = m23.x; bfrag.w = m23.y;
            const f32x4 acc = __builtin_amdgcn_mfma_f32_16x16x16f16(afrag, bfrag, cb, 0, 0, 0);
            const h2 e01 = __builtin_elementwise_max(CVTPK(acc.x, acc.y), hz);
            const h2 e23 = __builtin_elementwise_max(CVTPK(acc.z, acc.w), hz);
            const float wp = FDOT2(e01, wxp01, FDOT2(e23, wxp23, 0.f));
            const unsigned gm = (s != j1) ? 0x3C003C00u : 0u;
            const h2 gu = __builtin_bit_cast(h2, gm);
            g01_1 = e01 * gu + g01_1;
            g23_1 = e23 * gu + g23_1;
            Sw1 += wp;
            Swx1 = fmaf(wp, xs4.x, Swx1);
            Swy1 = fmaf(wp, xs4.y, Swy1);
            Swz1 = fmaf(wp, xs4.z, Swz1);
        }
    }

#pragma unroll
    for (int off = 1; off < 64; off <<= 1) {
        Sw0  += __shfl_xor(Sw0,  off, 64);  Sw1  += __shfl_xor(Sw1,  off, 64);
        Swx0 += __shfl_xor(Swx0, off, 64);  Swx1 += __shfl_xor(Swx1, off, 64);
        Swy0 += __shfl_xor(Swy0, off, 64);  Swy1 += __shfl_xor(Swy1, off, 64);
        Swz0 += __shfl_xor(Swz0, off, 64);  Swz1 += __shfl_xor(Swz1, off, 64);
    }
#pragma unroll
    for (int off = 1; off < 16; off <<= 1) {
        g01_0 = g01_0 + __builtin_bit_cast(h2, __shfl_xor(__builtin_bit_cast(int, g01_0), off, 64));
        g23_0 = g23_0 + __builtin_bit_cast(h2, __shfl_xor(__builtin_bit_cast(int, g23_0), off, 64));
        g01_1 = g01_1 + __builtin_bit_cast(h2, __shfl_xor(__builtin_bit_cast(int, g01_1), off, 64));
        g23_1 = g23_1 + __builtin_bit_cast(h2, __shfl_xor(__builtin_bit_cast(int, g23_1), off, 64));
    }
    if ((lane & 15) == 0) {
        *(float4*)&sg[w][4 * g]     = make_float4((float)g01_0.x, (float)g01_0.y,
                                                  (float)g23_0.x, (float)g23_0.y);
        *(float4*)&sg[w + 4][4 * g] = make_float4((float)g01_1.x, (float)g01_1.y,
                                                  (float)g23_1.x, (float)g23_1.y);
    }
    __syncthreads();

    const int is0 = (lane < 16);
    const int is1 = (lane >= 32 && lane < 48);
    if (is0 || is1) {
        const int f = lane & 15;
        const int slot = is0 ? w : (w + 4);
        const int jm   = is0 ? j0 : j1;
        const float SwS = is0 ? Sw0  : Sw1;
        const float SxS = is0 ? Swx0 : Swx1;
        const float SyS = is0 ? Swy0 : Swy1;
        const float SzS = is0 ? Swz0 : Swz1;
        const float4 xjm = is0 ? xj0 : xj1;
        const size_t nj = (size_t)b * NN + jm;
        float hd = bh1_l[f];
        float hv = 0.f;
#pragma unroll
        for (int k = 0; k < NF; ++k) {
            const float hjk = h_in[nj * NF + k];
            hd = fmaf(hjk, sWh1s[k * NF + f], hd);
            hv = fmaf(hjk, Wv_l[k], hv);
        }
#pragma unroll
        for (int k = 0; k < NF; ++k) {
            hd = fmaf(sg[slot][k], sWh1s[(NF + k) * NF + f], hd);
        }
        const float hnew = h_in[nj * NF + f] + fmaxf(hd, 0.f);
        sh_new[slot][f] = hnew;
        if (!final_layer) h_out[nj * NF + f] = hnew;
        if (f < 3) {
            const float xc = (f == 0) ? xjm.x : ((f == 1) ? xjm.y : xjm.z);
            const float Sc = (f == 0) ? SxS  : ((f == 1) ? SyS  : SzS);
            const float agg = (SwS * xc - Sc) * (1.f / 255.f);
            const float xnew = xc + agg + vs[nj * 3 + f] * hv;
            if (final_layer) x_out[nj * 3 + f] = xnew;
            else             x_out[nj * 4 + f] = xnew;
        }
        if (!final_layer && f == 3) x_out[nj * 4 + 3] = 0.f;
    }

    if (!final_layer) {
        __syncthreads();
        if (tid < 128) {
            const int jd = tid >> 4, k = tid & 15;
            float u = 0.f, v = sbe1n[k];
#pragma unroll
            for (int f = 0; f < NF; ++f) {
                const float hf = sh_new[jd][f];
                u = fmaf(hf, sWa[k * NF + f], u);
                v = fmaf(hf, sWb[k * NF + f], v);
            }
            su_out[(n0 + jd) * NF + k] = u;
            sv_out[(n0 + jd) * NF + k] = v;
        }
    }
}

extern "C" void kernel_launch(void* const* d_in, const int* in_sizes, int n_in,
                              void* d_out, int out_size, void* d_ws, size_t ws_size,
                              hipStream_t stream) {
    const float* xs      = (const float*)d_in[0];
    const float* vs      = (const float*)d_in[1];
    const float* charges = (const float*)d_in[2];
    const float* W_in    = (const float*)d_in[3];
    const float* b_in    = (const float*)d_in[4];
    const float* W_v     = (const float*)d_in[5];
    const float* We1     = (const float*)d_in[6];
    const float* be1     = (const float*)d_in[7];
    const float* We2     = (const float*)d_in[8];
    const float* be2     = (const float*)d_in[9];
    const float* Wx      = (const float*)d_in[10];
    const float* Wh1     = (const float*)d_in[11];
    const float* bh1     = (const float*)d_in[12];
    // d_in[13]=src, d_in[14]=dst: fully-connected pattern, computed analytically.

    float* ws = (float*)d_ws;
    float* xA  = ws + XA_OFF;
    float* xB  = ws + XB_OFF;
    float* hA  = ws + HA_OFF;
    float* hB  = ws + HB_OFF;
    float* suA = ws + SUA_OFF;
    float* svA = ws + SVA_OFF;
    float* suB = ws + SUB_OFF;
    float* svB = ws + SVB_OFF;
    float* out = (float*)d_out;

    // L0 (init fused): writes xA, hA, suA, svA
    hipLaunchKernelGGL(layer0_kernel, dim3(1024), dim3(256), 0, stream,
                       xs, vs, charges, W_in, b_in,
                       W_v + 0 * 16, We1 + 0 * 528, be1 + 0 * 16, We2 + 0 * 256,
                       be2 + 0 * 16, Wx + 0 * 16, Wh1 + 0 * 512, bh1 + 0 * 16,
                       We1 + 1 * 528, be1 + 1 * 16,
                       xA, hA, suA, svA);
    // L1
    hipLaunchKernelGGL(layer_kernel, dim3(1024), dim3(256), 0, stream,
                       xA, hA, suA, svA, xB, hB, suB, svB,
                       vs, W_v + 1 * 16, We1 + 1 * 528, We2 + 1 * 256,
                       be2 + 1 * 16, Wx + 1 * 16, Wh1 + 1 * 512, bh1 + 1 * 16,
                       We1 + 2 * 528, be1 + 2 * 16, 0);
    // L2 (final)
    hipLaunchKernelGGL(layer_kernel, dim3(1024), dim3(256), 0, stream,
                       xB, hB, suB, svB, out, hA, suA, svA,
                       vs, W_v + 2 * 16, We1 + 2 * 528, We2 + 2 * 256,
                       be2 + 2 * 16, Wx + 2 * 16, Wh1 + 2 * 512, bh1 + 2 * 16,
                       We1 + 2 * 528, be1 + 2 * 16, 1);
}